// Round 7
// baseline (92.835 us; speedup 1.0000x reference)
//
#include <hip/hip_runtime.h>
#include <hip/hip_bf16.h>

// Decorrelation: out[n,v] = x[n,v] + sum_{c<v} x[n,c] * S_{c,v}(x[n,c])
// Uniform knots => closed-form cubic B-spline; fold basis·params into a
// per-(segment, pair) cubic coefficient table. Two copies of the table:
// LDS (even l) and global/L1 via d_ws (odd l) — splits the 120 coefficient
// reads across the LDS pipe and the vector-L1 pipe.

constexpr int D    = 16;
constexpr int K    = 11;          // params rows (degree+1)
constexpr int L    = 120;         // D*(D-1)/2
constexpr int NSEG = 8;           // K - SPLINE_DEG
// per-segment stride in floats: 120 cells * 4 + 4 pad => 484.
// LDS: dword index = s*484 + 4l : 484 % 32 == 4, so the 8 segment values map
// to disjoint bank quads -> conflict-free ds_read_b128. Same stride reused
// for the global copy so one byte-offset array serves both.
constexpr int SEG_STRIDE = L * 4 + 4;

__device__ __forceinline__ void coef(const float* __restrict__ p, int s, int l,
                                     float4* c) {
  float p0 = p[(s + 0) * L + l];
  float p1 = p[(s + 1) * L + l];
  float p2 = p[(s + 2) * L + l];
  float p3 = p[(s + 3) * L + l];
  c->x = (p0 + 4.0f * p1 + p2) * (1.0f / 6.0f);
  c->y = (p2 - p0) * 0.5f;
  c->z = (p0 - 2.0f * p1 + p2) * 0.5f;
  c->w = (p3 - p0) * (1.0f / 6.0f) + (p1 - p2) * 0.5f;
}

// Kernel 1 (1 block): write global coefficient table into d_ws + penalties.
__global__ __launch_bounds__(256) void build_and_pen(
    const float* __restrict__ params, float* __restrict__ gT,
    float* __restrict__ pen_out) {
  for (int idx = threadIdx.x; idx < NSEG * L; idx += 256) {
    int s = idx / L;
    int l = idx - s * L;
    float4 c;
    coef(params, s, l, &c);
    *reinterpret_cast<float4*>(&gT[s * SEG_STRIDE + l * 4]) = c;
  }
  float s2 = 0.0f, s1 = 0.0f, s0 = 0.0f;
  for (int i = threadIdx.x; i < (K - 2) * L; i += 256) {
    float v = params[i + 2 * L] - 2.0f * params[i + L] + params[i];
    s2 += v * v;
  }
  for (int i = threadIdx.x; i < (K - 1) * L; i += 256) {
    float v = params[i + L] - params[i];
    s1 += v * v;
  }
  for (int i = threadIdx.x; i < K * L; i += 256) {
    float v = params[i];
    s0 += v * v;
  }
#pragma unroll
  for (int off = 32; off > 0; off >>= 1) {
    s2 += __shfl_down(s2, off);
    s1 += __shfl_down(s1, off);
    s0 += __shfl_down(s0, off);
  }
  __shared__ float r[3][4];
  int wid = threadIdx.x >> 6, lane = threadIdx.x & 63;
  if (lane == 0) { r[0][wid] = s2; r[1][wid] = s1; r[2][wid] = s0; }
  __syncthreads();
  if (threadIdx.x == 0) {
    pen_out[0] = r[0][0] + r[0][1] + r[0][2] + r[0][3];
    pen_out[1] = r[1][0] + r[1][1] + r[1][2] + r[1][3];
    pen_out[2] = r[2][0] + r[2][1] + r[2][2] + r[2][3];
  }
}

__global__ __launch_bounds__(256) void decor_kernel(
    const float* __restrict__ x, const float* __restrict__ params,
    const float* __restrict__ prange, const float* __restrict__ gT,
    float* __restrict__ out, int N) {
  __shared__ float T[NSEG * SEG_STRIDE];  // 15488 B

  // Build LDS copy of the coefficient table.
  for (int idx = threadIdx.x; idx < NSEG * L; idx += 256) {
    int s = idx / L;
    int l = idx - s * L;
    float4 c;
    coef(params, s, l, &c);
    *reinterpret_cast<float4*>(&T[s * SEG_STRIDE + l * 4]) = c;
  }
  __syncthreads();

  int n = blockIdx.x * 256 + threadIdx.x;
  if (n >= N) return;

  // Load one sample row (coalesced float4s).
  float xv[D];
  const float4* xr = reinterpret_cast<const float4*>(x + (size_t)n * D);
#pragma unroll
  for (int i = 0; i < D / 4; ++i) {
    float4 v = xr[i];
    xv[4 * i + 0] = v.x; xv[4 * i + 1] = v.y;
    xv[4 * i + 2] = v.z; xv[4 * i + 3] = v.w;
  }

  // Per-dim: local coordinate u and segment BYTE offset (valid for T and gT).
  float u[D];
  int   sb[D];
#pragma unroll
  for (int d = 0; d < D; ++d) {
    float lo0  = prange[d];
    float hi0  = prange[D + d];
    float span = hi0 - lo0;
    float lo   = lo0 - 0.1f * span;
    float hi   = hi0 + 0.1f * span;
    float eps  = 1e-6f * (hi - lo);
    float hinv = (float)NSEG / (hi - lo);
    float xc   = fminf(fmaxf(xv[d], lo), hi - eps);
    float t    = (xc - lo) * hinv;          // in [0, 8)
    int   s    = (int)t;
    s          = s > NSEG - 1 ? NSEG - 1 : s;
    u[d]       = t - (float)s;
    sb[d]      = s * (SEG_STRIDE * 4);      // byte offset
  }

  float acc[D];
#pragma unroll
  for (int v = 0; v < D; ++v) acc[v] = xv[v];

  const char* Tb = reinterpret_cast<const char*>(T);
  const char* Gb = reinterpret_cast<const char*>(gT);
#pragma unroll
  for (int v = 1; v < D; ++v) {
    const int lbase = v * (v - 1) / 2;
#pragma unroll
    for (int c = 0; c < v; ++c) {
      const int l = lbase + c;
      // Split coefficient reads across LDS (even l) and L1/global (odd l).
      const float4 cf =
          (l & 1) ? *reinterpret_cast<const float4*>(Gb + sb[c] + l * 16)
                  : *reinterpret_cast<const float4*>(Tb + sb[c] + l * 16);
      // Horner: q = c0 + u(c1 + u(c2 + u*c3)); acc += q * x_c
      float q = fmaf(fmaf(fmaf(cf.w, u[c], cf.z), u[c], cf.y), u[c], cf.x);
      acc[v] = fmaf(q, xv[c], acc[v]);
    }
  }

  float4* orow = reinterpret_cast<float4*>(out + (size_t)n * D);
#pragma unroll
  for (int i = 0; i < D / 4; ++i) {
    orow[i] = make_float4(acc[4 * i + 0], acc[4 * i + 1],
                          acc[4 * i + 2], acc[4 * i + 3]);
  }
}

extern "C" void kernel_launch(void* const* d_in, const int* in_sizes, int n_in,
                              void* d_out, int out_size, void* d_ws,
                              size_t ws_size, hipStream_t stream) {
  const float* x      = (const float*)d_in[0];
  const float* params = (const float*)d_in[1];
  const float* prange = (const float*)d_in[2];
  float* out = (float*)d_out;
  float* gT  = (float*)d_ws;      // 8*484*4 = 15488 B of scratch
  int N = in_sizes[0] / D;

  build_and_pen<<<1, 256, 0, stream>>>(params, gT, out + (size_t)N * D);
  int blocks = (N + 255) / 256;
  decor_kernel<<<blocks, 256, 0, stream>>>(x, params, prange, gT, out, N);
}

// Round 9
// 83.125 us; speedup vs baseline: 1.1168x; 1.1168x over previous
//
#include <hip/hip_runtime.h>
#include <hip/hip_bf16.h>

// Decorrelation: out[n,v] = x[n,v] + sum_{c<v} x[n,c] * S_{c,v}(x[n,c])
// Uniform knots => closed-form cubic B-spline; fold basis·params into a
// per-(segment, pair) cubic coefficient table in LDS, PACKED AS 4x bf16
// (8 B/pair) so each pair costs one ds_read_b64 instead of ds_read_b128.
// Horner evaluation in f32. Penalties fused into block 0.
//
// LDS layout: dword index = s*242 + l*2. Per-l, the 8 segment bases map to
// bank pairs {0,1},{18,19},{4,5},{22,23},{8,9},{26,27},{12,13},{30,31}
// -> all 16 banks distinct -> conflict-free ds_read_b64.

constexpr int D    = 16;
constexpr int K    = 11;          // params rows (degree+1)
constexpr int L    = 120;         // D*(D-1)/2
constexpr int NSEG = 8;           // K - SPLINE_DEG
constexpr int SEG_DW = L * 2 + 2; // 242 dwords per segment (2 pad)

__device__ __forceinline__ unsigned bf16rne(float f) {
  unsigned u = __float_as_uint(f);
  return (u + 0x7fffu + ((u >> 16) & 1u)) >> 16;
}

__global__ __launch_bounds__(256) void decor_fused(
    const float* __restrict__ x, const float* __restrict__ params,
    const float* __restrict__ prange, float* __restrict__ out, int N) {
  __shared__ unsigned T2[NSEG * SEG_DW];  // 7744 B

  // Build packed coefficient table: S(u) = c0 + c1 u + c2 u^2 + c3 u^3.
  for (int idx = threadIdx.x; idx < NSEG * L; idx += 256) {
    int s = idx / L;
    int l = idx - s * L;
    float p0 = params[(s + 0) * L + l];
    float p1 = params[(s + 1) * L + l];
    float p2 = params[(s + 2) * L + l];
    float p3 = params[(s + 3) * L + l];
    float c0 = (p0 + 4.0f * p1 + p2) * (1.0f / 6.0f);
    float c1 = (p2 - p0) * 0.5f;
    float c2 = (p0 - 2.0f * p1 + p2) * 0.5f;
    float c3 = (p3 - p0) * (1.0f / 6.0f) + (p1 - p2) * 0.5f;
    T2[s * SEG_DW + l * 2 + 0] = (bf16rne(c1) << 16) | bf16rne(c0);
    T2[s * SEG_DW + l * 2 + 1] = (bf16rne(c3) << 16) | bf16rne(c2);
  }

  // Penalties in block 0 only (out layout: [N*D main, s2, s1, s0]).
  if (blockIdx.x == 0) {
    float s2 = 0.0f, s1 = 0.0f, s0 = 0.0f;
    for (int i = threadIdx.x; i < (K - 2) * L; i += 256) {
      float v = params[i + 2 * L] - 2.0f * params[i + L] + params[i];
      s2 += v * v;
    }
    for (int i = threadIdx.x; i < (K - 1) * L; i += 256) {
      float v = params[i + L] - params[i];
      s1 += v * v;
    }
    for (int i = threadIdx.x; i < K * L; i += 256) {
      float v = params[i];
      s0 += v * v;
    }
#pragma unroll
    for (int off = 32; off > 0; off >>= 1) {
      s2 += __shfl_down(s2, off);
      s1 += __shfl_down(s1, off);
      s0 += __shfl_down(s0, off);
    }
    __shared__ float r[3][4];
    int wid = threadIdx.x >> 6, lane = threadIdx.x & 63;
    if (lane == 0) { r[0][wid] = s2; r[1][wid] = s1; r[2][wid] = s0; }
    __syncthreads();
    if (threadIdx.x == 0) {
      float* o = out + (size_t)N * D;
      o[0] = r[0][0] + r[0][1] + r[0][2] + r[0][3];
      o[1] = r[1][0] + r[1][1] + r[1][2] + r[1][3];
      o[2] = r[2][0] + r[2][1] + r[2][2] + r[2][3];
    }
  }
  __syncthreads();

  int n = blockIdx.x * 256 + threadIdx.x;
  if (n >= N) return;

  // Load one sample row (coalesced float4s).
  float xv[D];
  const float4* xr = reinterpret_cast<const float4*>(x + (size_t)n * D);
#pragma unroll
  for (int i = 0; i < D / 4; ++i) {
    float4 v = xr[i];
    xv[4 * i + 0] = v.x; xv[4 * i + 1] = v.y;
    xv[4 * i + 2] = v.z; xv[4 * i + 3] = v.w;
  }

  // Per-dim: local coordinate u and segment BYTE offset into T2.
  float u[D];
  int   sb[D];
#pragma unroll
  for (int d = 0; d < D; ++d) {
    float lo0  = prange[d];
    float hi0  = prange[D + d];
    float span = hi0 - lo0;
    float lo   = lo0 - 0.1f * span;
    float hi   = hi0 + 0.1f * span;
    float eps  = 1e-6f * (hi - lo);
    float hinv = (float)NSEG / (hi - lo);
    float xc   = fminf(fmaxf(xv[d], lo), hi - eps);
    float t    = (xc - lo) * hinv;          // in [0, 8)
    int   s    = (int)t;
    s          = s > NSEG - 1 ? NSEG - 1 : s;
    u[d]       = t - (float)s;
    sb[d]      = s * (SEG_DW * 4);          // byte offset
  }

  float acc[D];
#pragma unroll
  for (int v = 0; v < D; ++v) acc[v] = xv[v];

  const char* Tb = reinterpret_cast<const char*>(T2);
#pragma unroll
  for (int v = 1; v < D; ++v) {
    const int lbase = v * (v - 1) / 2;
#pragma unroll
    for (int c = 0; c < v; ++c) {
      const int l = lbase + c;
      const uint2 dw = *reinterpret_cast<const uint2*>(Tb + sb[c] + l * 8);
      float c0 = __uint_as_float(dw.x << 16);
      float c1 = __uint_as_float(dw.x & 0xffff0000u);
      float c2 = __uint_as_float(dw.y << 16);
      float c3 = __uint_as_float(dw.y & 0xffff0000u);
      // Horner: q = c0 + u(c1 + u(c2 + u*c3)); acc += q * x_c
      float q = fmaf(fmaf(fmaf(c3, u[c], c2), u[c], c1), u[c], c0);
      acc[v] = fmaf(q, xv[c], acc[v]);
    }
  }

  float4* orow = reinterpret_cast<float4*>(out + (size_t)n * D);
#pragma unroll
  for (int i = 0; i < D / 4; ++i) {
    orow[i] = make_float4(acc[4 * i + 0], acc[4 * i + 1],
                          acc[4 * i + 2], acc[4 * i + 3]);
  }
}

extern "C" void kernel_launch(void* const* d_in, const int* in_sizes, int n_in,
                              void* d_out, int out_size, void* d_ws,
                              size_t ws_size, hipStream_t stream) {
  const float* x      = (const float*)d_in[0];
  const float* params = (const float*)d_in[1];
  const float* prange = (const float*)d_in[2];
  float* out = (float*)d_out;
  int N = in_sizes[0] / D;

  int blocks = (N + 255) / 256;
  decor_fused<<<blocks, 256, 0, stream>>>(x, params, prange, out, N);
}